// Round 1
// baseline (1471.700 us; speedup 1.0000x reference)
//
#include <hip/hip_runtime.h>
#include <stddef.h>

#define CCH 128   // channels
#define VT  64    // vertices per compute block

// ---------------- prep: A_t[c][o] = W1[o][c]-W2[o][c], W2_t[c][o] = W2[o][c]
__global__ void prep_weights(const float* __restrict__ w,
                             float* __restrict__ A_t, float* __restrict__ W2_t) {
    int i = blockIdx.x * 256 + threadIdx.x;    // i = c*128 + o, 16384 total
    int c = i >> 7, o = i & 127;
    float w2 = w[o * 256 + 128 + c];
    A_t[i]  = w[o * 256 + c] - w2;
    W2_t[i] = w2;
}

// ---------------- transpose x [128][N] -> x_t [N][128]
__global__ void transpose_x(const float* __restrict__ x, float* __restrict__ x_t, int N) {
    __shared__ float tile[32][33];
    int n0 = blockIdx.x * 32, c0 = blockIdx.y * 32;
    int tx = threadIdx.x, ty = threadIdx.y;    // (32,8)
    #pragma unroll
    for (int k = 0; k < 4; ++k) {
        int c = c0 + ty + k * 8, n = n0 + tx;
        tile[ty + k * 8][tx] = (n < N) ? x[(size_t)c * N + n] : 0.f;
    }
    __syncthreads();
    #pragma unroll
    for (int k = 0; k < 4; ++k) {
        int n = n0 + ty + k * 8, cc = c0 + tx;
        if (n < N) x_t[(size_t)n * CCH + cc] = tile[tx][ty + k * 8];
    }
}

// ---------------- scatter: g_sum[r] += x_t[g], counts[r] += 1 (32 lanes/edge)
__global__ void scatter_edges(const float4* __restrict__ x_t4,
                              const int* __restrict__ ridx, const int* __restrict__ gidx,
                              float* __restrict__ g_sum, int* __restrict__ counts, int E) {
    int t = blockIdx.x * blockDim.x + threadIdx.x;
    int e = t >> 5, l = t & 31;
    if (e >= E) return;
    int r = ridx[e], g = gidx[e];
    float4 v = x_t4[(size_t)g * 32 + l];
    float* dst = g_sum + (size_t)r * CCH + l * 4;
    atomicAdd(dst + 0, v.x);
    atomicAdd(dst + 1, v.y);
    atomicAdd(dst + 2, v.z);
    atomicAdd(dst + 3, v.w);
    if (l == 0) atomicAdd(counts + r, 1);
}

// ---------------- compute: out[:, n0:n0+VT] = mask * leaky(A@x + W2@gmean + bias)
__global__ __launch_bounds__(256) void compute_out(
        const float* __restrict__ x,      // [128][N]
        const float* __restrict__ g_sum,  // [N][128]
        const int*   __restrict__ counts, // [N]
        const float* __restrict__ A_t,    // [c][o] 128x128
        const float* __restrict__ W2_t,   // [c][o] 128x128
        const float* __restrict__ bias,   // [128]
        float* __restrict__ out,          // [128][N]
        int N) {
    __shared__ float xt[CCH][VT + 4];
    __shared__ float gt[CCH][VT + 4];
    int n0 = blockIdx.x * VT;
    int tid = threadIdx.x;

    // stage x[c][n0+v] -> xt[c][v]  (coalesced float4 row loads)
    {
        int v4 = (tid & 15) * 4;
        int cb = tid >> 4;
        #pragma unroll
        for (int k = 0; k < 8; ++k) {
            int c = cb + k * 16;
            float4 val = make_float4(0.f, 0.f, 0.f, 0.f);
            if (n0 + v4 < N)   // N%4==0, v4%4==0 -> whole chunk valid
                val = *(const float4*)(x + (size_t)c * N + n0 + v4);
            *(float4*)&xt[c][v4] = val;
        }
    }
    // stage g_sum[n0+v][c]/max(cnt,1) -> gt[c][v]  (transpose on the fly)
    {
        int v = tid >> 2;              // 0..63
        int cbase = (tid & 3) * 4;     // 0,4,8,12
        int n = n0 + v;
        float inv = 0.f;
        if (n < N) { int cnt = counts[n]; inv = 1.0f / (float)(cnt > 0 ? cnt : 1); }
        #pragma unroll
        for (int k = 0; k < 8; ++k) {
            int c4 = cbase + k * 16;
            float4 val = make_float4(0.f, 0.f, 0.f, 0.f);
            if (n < N) val = *(const float4*)(g_sum + (size_t)n * CCH + c4);
            gt[c4 + 0][v] = val.x * inv;
            gt[c4 + 1][v] = val.y * inv;
            gt[c4 + 2][v] = val.z * inv;
            gt[c4 + 3][v] = val.w * inv;
        }
    }
    __syncthreads();

    int l = tid & 31;      // channel group: o = 4l..4l+3
    int w = tid >> 5;      // vertex group:  v = 8w..8w+7
    float acc[4][8];
    #pragma unroll
    for (int i = 0; i < 4; ++i)
        #pragma unroll
        for (int j = 0; j < 8; ++j) acc[i][j] = 0.f;

    const float4* At4 = (const float4*)A_t;
    const float4* W24 = (const float4*)W2_t;
    for (int c = 0; c < CCH; ++c) {
        float4 a = At4[c * 32 + l];
        float4 b = W24[c * 32 + l];
        float4 x0 = *(const float4*)&xt[c][8 * w];
        float4 x1 = *(const float4*)&xt[c][8 * w + 4];
        float4 g0 = *(const float4*)&gt[c][8 * w];
        float4 g1 = *(const float4*)&gt[c][8 * w + 4];
        const float* ap = (const float*)&a;
        const float* bp = (const float*)&b;
        const float* xp0 = (const float*)&x0;
        const float* xp1 = (const float*)&x1;
        const float* gp0 = (const float*)&g0;
        const float* gp1 = (const float*)&g1;
        #pragma unroll
        for (int i = 0; i < 4; ++i) {
            #pragma unroll
            for (int j = 0; j < 4; ++j) {
                acc[i][j]     += ap[i] * xp0[j];
                acc[i][j]     += bp[i] * gp0[j];
                acc[i][j + 4] += ap[i] * xp1[j];
                acc[i][j + 4] += bp[i] * gp1[j];
            }
        }
    }

    // epilogue: + bias, empty-segment mask, leaky relu, coalesced float4 stores
    int vbase = n0 + 8 * w;
    if (vbase < N) {                  // N%8==0 -> all 8 valid
        float4 bi = *(const float4*)(bias + 4 * l);
        const float* bp = (const float*)&bi;
        float m[8];
        #pragma unroll
        for (int j = 0; j < 8; ++j) m[j] = (counts[vbase + j] > 0) ? 1.f : 0.f;
        #pragma unroll
        for (int i = 0; i < 4; ++i) {
            int o = 4 * l + i;
            float r[8];
            #pragma unroll
            for (int j = 0; j < 8; ++j) {
                float v = (acc[i][j] + bp[i]) * m[j];
                r[j] = (v >= 0.f) ? v : 0.3f * v;
            }
            *(float4*)(out + (size_t)o * N + vbase)     = make_float4(r[0], r[1], r[2], r[3]);
            *(float4*)(out + (size_t)o * N + vbase + 4) = make_float4(r[4], r[5], r[6], r[7]);
        }
    }
}

extern "C" void kernel_launch(void* const* d_in, const int* in_sizes, int n_in,
                              void* d_out, int out_size, void* d_ws, size_t ws_size,
                              hipStream_t stream) {
    const float* x      = (const float*)d_in[0];  // [1,128,N]
    const float* weight = (const float*)d_in[1];  // [128,256]
    const float* bias   = (const float*)d_in[2];  // [128]
    const int*   ridx   = (const int*)d_in[3];    // [E]
    const int*   gidx   = (const int*)d_in[4];    // [E]
    float* out = (float*)d_out;

    int N = in_sizes[0] / CCH;   // 50000
    int E = in_sizes[3];         // 800000

    char* ws = (char*)d_ws;
    size_t xt_bytes  = (size_t)N * CCH * sizeof(float);   // 25.6 MB
    size_t gs_bytes  = (size_t)N * CCH * sizeof(float);   // 25.6 MB
    size_t cnt_bytes = (size_t)N * sizeof(int);           // 200 KB
    float* x_t   = (float*)ws;
    float* g_sum = (float*)(ws + xt_bytes);
    int*   counts= (int*)  (ws + xt_bytes + gs_bytes);
    float* A_t   = (float*)(ws + xt_bytes + gs_bytes + cnt_bytes);
    float* W2_t  = A_t + CCH * CCH;

    // zero the accumulators (g_sum + counts are contiguous)
    hipMemsetAsync(g_sum, 0, gs_bytes + cnt_bytes, stream);

    prep_weights<<<(CCH * CCH) / 256, 256, 0, stream>>>(weight, A_t, W2_t);

    dim3 tg((N + 31) / 32, CCH / 32);
    transpose_x<<<tg, dim3(32, 8), 0, stream>>>(x, x_t, N);

    long long threads = (long long)E * 32;
    int sblocks = (int)((threads + 255) / 256);
    scatter_edges<<<sblocks, 256, 0, stream>>>((const float4*)x_t, ridx, gidx,
                                               g_sum, counts, E);

    compute_out<<<(N + VT - 1) / VT, 256, 0, stream>>>(x, g_sum, counts,
                                                       A_t, W2_t, bias, out, N);
}

// Round 2
// 319.784 us; speedup vs baseline: 4.6022x; 4.6022x over previous
//
#include <hip/hip_runtime.h>
#include <stddef.h>

#define CCH 128   // channels
#define VT  32    // vertices per compute block

// ---------------- prep: A_t[c][o] = W1[o][c]-W2[o][c], W2_t[c][o] = W2[o][c]
__global__ void prep_weights(const float* __restrict__ w,
                             float* __restrict__ A_t, float* __restrict__ W2_t) {
    int i = blockIdx.x * 256 + threadIdx.x;    // i = c*128 + o, 16384 total
    int c = i >> 7, o = i & 127;
    float w2 = w[o * 256 + 128 + c];
    A_t[i]  = w[o * 256 + c] - w2;
    W2_t[i] = w2;
}

// ---------------- transpose x [128][N] -> x_t [N][128]
__global__ void transpose_x(const float* __restrict__ x, float* __restrict__ x_t, int N) {
    __shared__ float tile[32][33];
    int n0 = blockIdx.x * 32, c0 = blockIdx.y * 32;
    int tx = threadIdx.x, ty = threadIdx.y;    // (32,8)
    #pragma unroll
    for (int k = 0; k < 4; ++k) {
        int c = c0 + ty + k * 8, n = n0 + tx;
        tile[ty + k * 8][tx] = (n < N) ? x[(size_t)c * N + n] : 0.f;
    }
    __syncthreads();
    #pragma unroll
    for (int k = 0; k < 4; ++k) {
        int n = n0 + ty + k * 8, cc = c0 + tx;
        if (n < N) x_t[(size_t)n * CCH + cc] = tile[tx][ty + k * 8];
    }
}

// ---------------- CSR build: histogram
__global__ void hist_kernel(const int* __restrict__ ridx, int* __restrict__ counts, int E) {
    int e = blockIdx.x * 256 + threadIdx.x;
    if (e < E) atomicAdd(&counts[ridx[e]], 1);
}

// ---------------- CSR build: exclusive scan (single block, 1024 threads)
__global__ __launch_bounds__(1024) void scan_offsets(const int* __restrict__ counts,
                                                     int* __restrict__ offsets, int N) {
    __shared__ int part[1024];
    int t = threadIdx.x;
    int chunk = (N + 1023) >> 10;
    int base = t * chunk;
    int s = 0;
    for (int i = 0; i < chunk; ++i) {
        int idx = base + i;
        if (idx < N) s += counts[idx];
    }
    part[t] = s;
    __syncthreads();
    for (int d = 1; d < 1024; d <<= 1) {
        int v = (t >= d) ? part[t - d] : 0;
        __syncthreads();
        part[t] += v;
        __syncthreads();
    }
    int run = (t > 0) ? part[t - 1] : 0;
    for (int i = 0; i < chunk; ++i) {
        int idx = base + i;
        if (idx < N) { offsets[idx] = run; run += counts[idx]; }
    }
    if (t == 1023) offsets[N] = part[1023];
}

// ---------------- CSR build: fill edge lists
__global__ void fill_csr(const int* __restrict__ ridx, const int* __restrict__ gidx,
                         const int* __restrict__ offsets, int* __restrict__ cursor,
                         int* __restrict__ csr, int E) {
    int e = blockIdx.x * 256 + threadIdx.x;
    if (e >= E) return;
    int r = ridx[e];
    int p = atomicAdd(&cursor[r], 1);
    csr[offsets[r] + p] = gidx[e];
}

// ---------------- fused: gather-mean (CSR) + dual GEMM + bias + mask + leaky
__global__ __launch_bounds__(256) void fused_out(
        const float* __restrict__ x,       // [128][N]
        const float* __restrict__ x_t,     // [N][128]
        const int*   __restrict__ offsets, // [N+1]
        const int*   __restrict__ csr,     // [E]
        const float* __restrict__ A_t,     // [c][o] 128x128
        const float* __restrict__ W2_t,    // [c][o] 128x128
        const float* __restrict__ bias,    // [128]
        float* __restrict__ out,           // [128][N]
        int N) {
    __shared__ float xt[CCH][VT + 4];
    __shared__ float gt[CCH][VT + 4];
    int n0 = blockIdx.x * VT;
    int tid = threadIdx.x;

    // stage x[c][n0..n0+31] -> xt[c][v]  (coalesced float4)
    #pragma unroll
    for (int k = 0; k < 4; ++k) {
        int idx = k * 256 + tid;
        int c = idx >> 3;
        int f4 = (idx & 7) * 4;
        float4 val = make_float4(0.f, 0.f, 0.f, 0.f);
        if (n0 + f4 < N)     // N%4==0 -> whole float4 in bounds
            val = *(const float4*)(x + (size_t)c * N + n0 + f4);
        *(float4*)&xt[c][f4] = val;
    }

    // phase A: per-wave vertex gather; lane l owns channels 2l,2l+1
    {
        int w = tid >> 6;     // wave 0..3
        int l = tid & 63;     // lane
        const float2* xt2 = (const float2*)x_t;
        for (int i = 0; i < 8; ++i) {
            int v = w * 8 + i;
            int n = n0 + v;
            float2 acc = make_float2(0.f, 0.f);
            int deg = 0;
            if (n < N) {
                int off = offsets[n];
                deg = offsets[n + 1] - off;
                int k = 0;
                for (; k + 4 <= deg; k += 4) {
                    int g0 = csr[off + k], g1 = csr[off + k + 1];
                    int g2 = csr[off + k + 2], g3 = csr[off + k + 3];
                    float2 a = xt2[(size_t)g0 * 64 + l];
                    float2 b = xt2[(size_t)g1 * 64 + l];
                    float2 c2 = xt2[(size_t)g2 * 64 + l];
                    float2 d2 = xt2[(size_t)g3 * 64 + l];
                    acc.x += (a.x + b.x) + (c2.x + d2.x);
                    acc.y += (a.y + b.y) + (c2.y + d2.y);
                }
                for (; k < deg; ++k) {
                    int g = csr[off + k];
                    float2 a = xt2[(size_t)g * 64 + l];
                    acc.x += a.x; acc.y += a.y;
                }
            }
            float inv = (deg > 0) ? 1.f / (float)deg : 0.f;
            gt[2 * l][v]     = acc.x * inv;
            gt[2 * l + 1][v] = acc.y * inv;
        }
    }
    __syncthreads();

    // phase B: out[4l..4l+3][vbase..vbase+3] = leaky(A@x + W2@gmean + bias)
    int l = tid & 31;     // o quad
    int w = tid >> 5;     // vertex quad 0..7
    float acc[4][4];
    #pragma unroll
    for (int i = 0; i < 4; ++i)
        #pragma unroll
        for (int j = 0; j < 4; ++j) acc[i][j] = 0.f;

    const float4* At4 = (const float4*)A_t;
    const float4* W24 = (const float4*)W2_t;
    for (int c = 0; c < CCH; ++c) {
        float4 a = At4[c * 32 + l];
        float4 b = W24[c * 32 + l];
        float4 xv = *(const float4*)&xt[c][4 * w];
        float4 gv = *(const float4*)&gt[c][4 * w];
        const float* ap = (const float*)&a;
        const float* bp = (const float*)&b;
        const float* xp = (const float*)&xv;
        const float* gp = (const float*)&gv;
        #pragma unroll
        for (int i = 0; i < 4; ++i)
            #pragma unroll
            for (int j = 0; j < 4; ++j)
                acc[i][j] += ap[i] * xp[j] + bp[i] * gp[j];
    }

    // epilogue
    int vbase = n0 + 4 * w;
    if (vbase < N) {                 // N%4==0 -> all 4 valid
        float4 bi = *(const float4*)(bias + 4 * l);
        const float* bp = (const float*)&bi;
        float m[4];
        #pragma unroll
        for (int j = 0; j < 4; ++j)
            m[j] = (offsets[vbase + j + 1] - offsets[vbase + j]) > 0 ? 1.f : 0.f;
        #pragma unroll
        for (int i = 0; i < 4; ++i) {
            int o = 4 * l + i;
            float r[4];
            #pragma unroll
            for (int j = 0; j < 4; ++j) {
                float v = (acc[i][j] + bp[i]) * m[j];
                r[j] = (v >= 0.f) ? v : 0.3f * v;
            }
            *(float4*)(out + (size_t)o * N + vbase) = make_float4(r[0], r[1], r[2], r[3]);
        }
    }
}

extern "C" void kernel_launch(void* const* d_in, const int* in_sizes, int n_in,
                              void* d_out, int out_size, void* d_ws, size_t ws_size,
                              hipStream_t stream) {
    const float* x      = (const float*)d_in[0];  // [1,128,N]
    const float* weight = (const float*)d_in[1];  // [128,256]
    const float* bias   = (const float*)d_in[2];  // [128]
    const int*   ridx   = (const int*)d_in[3];    // [E]
    const int*   gidx   = (const int*)d_in[4];    // [E]
    float* out = (float*)d_out;

    int N = in_sizes[0] / CCH;   // 50000
    int E = in_sizes[3];         // 800000

    char* ws = (char*)d_ws;
    size_t xt_bytes  = (size_t)N * CCH * sizeof(float);   // 25.6 MB
    size_t cnt_bytes = (size_t)N * sizeof(int);           // 200 KB (x2: counts+cursor)
    size_t off_bytes = (size_t)(N + 16) * sizeof(int);    // offsets, padded for alignment
    size_t csr_bytes = (size_t)E * sizeof(int);           // 3.2 MB

    float* x_t    = (float*)ws;
    int*   counts = (int*)(ws + xt_bytes);
    int*   cursor = (int*)(ws + xt_bytes + cnt_bytes);
    int*   offsets= (int*)(ws + xt_bytes + 2 * cnt_bytes);
    int*   csr    = (int*)(ws + xt_bytes + 2 * cnt_bytes + off_bytes);
    float* A_t    = (float*)(ws + xt_bytes + 2 * cnt_bytes + off_bytes + csr_bytes);
    float* W2_t   = A_t + CCH * CCH;

    // zero counts + cursor (adjacent)
    hipMemsetAsync(counts, 0, 2 * cnt_bytes, stream);

    prep_weights<<<(CCH * CCH) / 256, 256, 0, stream>>>(weight, A_t, W2_t);

    dim3 tg((N + 31) / 32, CCH / 32);
    transpose_x<<<tg, dim3(32, 8), 0, stream>>>(x, x_t, N);

    int eblocks = (E + 255) / 256;
    hist_kernel<<<eblocks, 256, 0, stream>>>(ridx, counts, E);
    scan_offsets<<<1, 1024, 0, stream>>>(counts, offsets, N);
    fill_csr<<<eblocks, 256, 0, stream>>>(ridx, gidx, offsets, cursor, csr, E);

    fused_out<<<(N + VT - 1) / VT, 256, 0, stream>>>(x, x_t, offsets, csr,
                                                     A_t, W2_t, bias, out, N);
}

// Round 3
// 249.366 us; speedup vs baseline: 5.9018x; 1.2824x over previous
//
#include <hip/hip_runtime.h>
#include <stddef.h>

#define CCH 128   // channels
#define VT  32    // vertices per compute block

// ---------------- prep: A_t[c][o] = W1[o][c]-W2[o][c], W2_t[c][o] = W2[o][c]
__global__ void prep_weights(const float* __restrict__ w,
                             float* __restrict__ A_t, float* __restrict__ W2_t) {
    int i = blockIdx.x * 256 + threadIdx.x;    // i = c*128 + o, 16384 total
    int c = i >> 7, o = i & 127;
    float w2 = w[o * 256 + 128 + c];
    A_t[i]  = w[o * 256 + c] - w2;
    W2_t[i] = w2;
}

// ---------------- transpose x [128][N] -> x_t [N][128]
__global__ __launch_bounds__(256) void transpose_x(const float* __restrict__ x,
                                                   float* __restrict__ x_t, int N) {
    __shared__ float tile[32][33];
    int n0 = blockIdx.x * 32, c0 = blockIdx.y * 32;
    int tid = threadIdx.x;
    // load 32c x 32n, coalesced 128B rows
    {
        int tx = tid & 31, r = tid >> 5;          // r = 0..7
        #pragma unroll
        for (int k = 0; k < 4; ++k) {
            int c = k * 8 + r;
            int n = n0 + tx;
            tile[c][tx] = (n < N) ? x[(size_t)(c0 + c) * N + n] : 0.f;
        }
    }
    __syncthreads();
    // write: thread -> n = tid>>3, cq = (tid&7)*4 ; float4 stores, 128B segments
    {
        int n = tid >> 3, cq = (tid & 7) * 4;
        if (n0 + n < N) {
            float4 v = make_float4(tile[cq][n], tile[cq + 1][n],
                                   tile[cq + 2][n], tile[cq + 3][n]);
            *(float4*)(x_t + (size_t)(n0 + n) * CCH + c0 + cq) = v;
        }
    }
}

// ---------------- CSR build: histogram
__global__ void hist_kernel(const int* __restrict__ ridx, int* __restrict__ counts, int E) {
    int e = blockIdx.x * 256 + threadIdx.x;
    if (e < E) atomicAdd(&counts[ridx[e]], 1);
}

// ---------------- CSR build: base offsets via global atomic (order-free)
__global__ void make_offsets(const int* __restrict__ counts, int* __restrict__ offs,
                             int* __restrict__ cursor, int* __restrict__ total, int N) {
    int n = blockIdx.x * 256 + threadIdx.x;
    if (n < N) {
        int b = atomicAdd(total, counts[n]);
        offs[n] = b;
        cursor[n] = b;
    }
}

// ---------------- CSR build: fill edge lists (cursor pre-seeded with base)
__global__ void fill_csr(const int* __restrict__ ridx, const int* __restrict__ gidx,
                         int* __restrict__ cursor, int* __restrict__ csr, int E) {
    int e = blockIdx.x * 256 + threadIdx.x;
    if (e >= E) return;
    int p = atomicAdd(&cursor[ridx[e]], 1);
    csr[p] = gidx[e];
}

// ---------------- fused: gather-mean (CSR) + dual GEMM + bias + mask + leaky
__global__ __launch_bounds__(256) void fused_out(
        const float* __restrict__ x,       // [128][N]
        const float* __restrict__ x_t,     // [N][128]
        const int*   __restrict__ offs,    // [N] base offsets
        const int*   __restrict__ counts,  // [N] degrees
        const int*   __restrict__ csr,     // [E]
        const float* __restrict__ A_t,     // [c][o] 128x128
        const float* __restrict__ W2_t,    // [c][o] 128x128
        const float* __restrict__ bias,    // [128]
        float* __restrict__ out,           // [128][N]
        int N) {
    __shared__ float xt[CCH][VT + 4];      // [c][v], padded for aligned float4
    __shared__ float gt[VT][CCH];          // [v][c]
    int n0 = blockIdx.x * VT;
    int tid = threadIdx.x;

    // stage x[c][n0..n0+31] -> xt[c][v]  (coalesced float4)
    #pragma unroll
    for (int k = 0; k < 4; ++k) {
        int idx = k * 256 + tid;
        int c = idx >> 3;
        int f4 = (idx & 7) * 4;
        float4 val = make_float4(0.f, 0.f, 0.f, 0.f);
        if (n0 + f4 < N)     // N%4==0 -> whole float4 in bounds
            val = *(const float4*)(x + (size_t)c * N + n0 + f4);
        *(float4*)&xt[c][f4] = val;
    }

    // phase A: half-wave per edge, float4 per lane (full 512B column per edge)
    {
        int w = tid >> 6;        // wave 0..3
        int l = tid & 63;
        int lq = l & 31;         // channel quad: channels 4lq..4lq+3
        int half = l >> 5;       // which edge of the pair
        const float4* xt4 = (const float4*)x_t;
        for (int i = 0; i < 8; ++i) {
            int v = w * 8 + i;
            int n = n0 + v;
            float4 acc = make_float4(0.f, 0.f, 0.f, 0.f);
            int deg = 0;
            if (n < N) {
                int off = __builtin_amdgcn_readfirstlane(offs[n]);
                deg     = __builtin_amdgcn_readfirstlane(counts[n]);
                int k = 0;
                for (; k + 8 <= deg; k += 8) {       // 8 edges, 4 loads/lane in flight
                    int g0 = csr[off + k +     half];
                    int g1 = csr[off + k + 2 + half];
                    int g2 = csr[off + k + 4 + half];
                    int g3 = csr[off + k + 6 + half];
                    float4 a = xt4[(size_t)g0 * 32 + lq];
                    float4 b = xt4[(size_t)g1 * 32 + lq];
                    float4 c2 = xt4[(size_t)g2 * 32 + lq];
                    float4 d2 = xt4[(size_t)g3 * 32 + lq];
                    acc.x += (a.x + b.x) + (c2.x + d2.x);
                    acc.y += (a.y + b.y) + (c2.y + d2.y);
                    acc.z += (a.z + b.z) + (c2.z + d2.z);
                    acc.w += (a.w + b.w) + (c2.w + d2.w);
                }
                for (; k + 2 <= deg; k += 2) {       // pairs
                    int g = csr[off + k + half];
                    float4 a = xt4[(size_t)g * 32 + lq];
                    acc.x += a.x; acc.y += a.y; acc.z += a.z; acc.w += a.w;
                }
                if (k < deg && half == 0) {          // odd leftover edge
                    int g = csr[off + k];
                    float4 a = xt4[(size_t)g * 32 + lq];
                    acc.x += a.x; acc.y += a.y; acc.z += a.z; acc.w += a.w;
                }
            }
            // combine the two halves
            acc.x += __shfl_xor(acc.x, 32);
            acc.y += __shfl_xor(acc.y, 32);
            acc.z += __shfl_xor(acc.z, 32);
            acc.w += __shfl_xor(acc.w, 32);
            float inv = (deg > 0) ? 1.f / (float)deg : 0.f;
            if (half == 0) {
                float4 r = make_float4(acc.x * inv, acc.y * inv, acc.z * inv, acc.w * inv);
                *(float4*)&gt[v][4 * lq] = r;        // contiguous 512B, conflict-free
            }
        }
    }
    __syncthreads();

    // phase B: out[4l..4l+3][vbase..vbase+3] = leaky(A@x + W2@gmean + bias)
    int l = tid & 31;     // o quad
    int w = tid >> 5;     // vertex quad 0..7
    float acc[4][4];
    #pragma unroll
    for (int i = 0; i < 4; ++i)
        #pragma unroll
        for (int j = 0; j < 4; ++j) acc[i][j] = 0.f;

    const float4* At4 = (const float4*)A_t;
    const float4* W24 = (const float4*)W2_t;
    for (int c = 0; c < CCH; ++c) {
        float4 a = At4[c * 32 + l];
        float4 b = W24[c * 32 + l];
        float4 xv = *(const float4*)&xt[c][4 * w];
        const float* ap = (const float*)&a;
        const float* bp = (const float*)&b;
        const float* xp = (const float*)&xv;
        float gp[4];
        #pragma unroll
        for (int j = 0; j < 4; ++j) gp[j] = gt[4 * w + j][c];   // LDS broadcast
        #pragma unroll
        for (int i = 0; i < 4; ++i)
            #pragma unroll
            for (int j = 0; j < 4; ++j)
                acc[i][j] += ap[i] * xp[j] + bp[i] * gp[j];
    }

    // epilogue
    int vbase = n0 + 4 * w;
    if (vbase < N) {                 // N%4==0 -> all 4 valid
        float4 bi = *(const float4*)(bias + 4 * l);
        const float* bp = (const float*)&bi;
        float m[4];
        #pragma unroll
        for (int j = 0; j < 4; ++j)
            m[j] = (counts[vbase + j] > 0) ? 1.f : 0.f;
        #pragma unroll
        for (int i = 0; i < 4; ++i) {
            int o = 4 * l + i;
            float r[4];
            #pragma unroll
            for (int j = 0; j < 4; ++j) {
                float v = (acc[i][j] + bp[i]) * m[j];
                r[j] = (v >= 0.f) ? v : 0.3f * v;
            }
            *(float4*)(out + (size_t)o * N + vbase) = make_float4(r[0], r[1], r[2], r[3]);
        }
    }
}

extern "C" void kernel_launch(void* const* d_in, const int* in_sizes, int n_in,
                              void* d_out, int out_size, void* d_ws, size_t ws_size,
                              hipStream_t stream) {
    const float* x      = (const float*)d_in[0];  // [1,128,N]
    const float* weight = (const float*)d_in[1];  // [128,256]
    const float* bias   = (const float*)d_in[2];  // [128]
    const int*   ridx   = (const int*)d_in[3];    // [E]
    const int*   gidx   = (const int*)d_in[4];    // [E]
    float* out = (float*)d_out;

    int N = in_sizes[0] / CCH;   // 50000
    int E = in_sizes[3];         // 800000

    char* ws = (char*)d_ws;
    size_t xt_bytes  = (size_t)N * CCH * sizeof(float);   // 25.6 MB
    size_t n_bytes   = (size_t)N * sizeof(int);           // 200 KB
    size_t tot_bytes = 16 * sizeof(int);                  // total + pad
    size_t csr_bytes = (size_t)E * sizeof(int);           // 3.2 MB

    float* x_t    = (float*)ws;
    int*   counts = (int*)(ws + xt_bytes);
    int*   total  = (int*)(ws + xt_bytes + n_bytes);      // adjacent to counts for one memset
    int*   offs   = (int*)(ws + xt_bytes + n_bytes + tot_bytes);
    int*   cursor = (int*)(ws + xt_bytes + 2 * n_bytes + tot_bytes);
    int*   csr    = (int*)(ws + xt_bytes + 3 * n_bytes + tot_bytes);
    float* A_t    = (float*)(ws + xt_bytes + 3 * n_bytes + tot_bytes + csr_bytes);
    float* W2_t   = A_t + CCH * CCH;

    // zero counts + total (adjacent)
    hipMemsetAsync(counts, 0, n_bytes + tot_bytes, stream);

    prep_weights<<<(CCH * CCH) / 256, 256, 0, stream>>>(weight, A_t, W2_t);

    dim3 tg((N + 31) / 32, CCH / 32);
    transpose_x<<<tg, 256, 0, stream>>>(x, x_t, N);

    int eblocks = (E + 255) / 256;
    int nblocks = (N + 255) / 256;
    hist_kernel<<<eblocks, 256, 0, stream>>>(ridx, counts, E);
    make_offsets<<<nblocks, 256, 0, stream>>>(counts, offs, cursor, total, N);
    fill_csr<<<eblocks, 256, 0, stream>>>(ridx, gidx, cursor, csr, E);

    fused_out<<<(N + VT - 1) / VT, 256, 0, stream>>>(x, x_t, offs, counts, csr,
                                                     A_t, W2_t, bias, out, N);
}